// Round 1
// baseline (12370.572 us; speedup 1.0000x reference)
//
#include <hip/hip_runtime.h>
#include <hip/hip_bf16.h>
#include <stdint.h>

// Problem constants
#define BATCH 64
#define SEQ   2048
#define KDIM  256
#define HIDD  256

typedef __attribute__((ext_vector_type(8))) short short8;
typedef __attribute__((ext_vector_type(4))) float f32x4;

__device__ __forceinline__ unsigned short f32_to_bf16_rne(float f) {
    union { float f; uint32_t u; } v; v.f = f;
    uint32_t u = v.u;
    uint32_t r = (u + 0x7FFFu + ((u >> 16) & 1u)) >> 16;
    return (unsigned short)r;
}
__device__ __forceinline__ float bf16_to_f32(unsigned short h) {
    union { float f; uint32_t u; } v; v.u = ((uint32_t)h) << 16;
    return v.f;
}

// ---------------------------------------------------------------------------
// Prep: transpose+cast weights to bf16 [n][k] layout (n = gate*256 + j), and
// fold biases (b_i + b_h) into a single [1024] fp32 vector.
// ---------------------------------------------------------------------------
struct PrepArgs {
    const float* Wi[4];
    const float* Wh[4];
    const float* bi[4];
    const float* bh[4];
    unsigned short* WT;    // [1024][256] bf16, from W_i*
    unsigned short* WhT;   // [1024][256] bf16, from W_h*
    float* biascat;        // [1024] fp32
};

__global__ __launch_bounds__(256) void prep_kernel(PrepArgs a) {
    int blk = blockIdx.x, tid = threadIdx.x;
    if (blk < 1024) {
        int n = blk, g = n >> 8, j = n & 255, k = tid;
        a.WT[(size_t)n * 256 + k] = f32_to_bf16_rne(a.Wi[g][(size_t)k * 256 + j]);
    } else if (blk < 2048) {
        int n = blk - 1024, g = n >> 8, j = n & 255, k = tid;
        a.WhT[(size_t)n * 256 + k] = f32_to_bf16_rne(a.Wh[g][(size_t)k * 256 + j]);
    } else if (blk < 2052) {
        int n = (blk - 2048) * 256 + tid;
        int g = n >> 8, j = n & 255;
        a.biascat[n] = a.bi[g][j] + a.bh[g][j];
    }
}

// ---------------------------------------------------------------------------
// Projection GEMM: P[t][b][n] = x[b,t,:] @ W_i[:,n] + bias[n], n = g*256+j.
// Output stored bf16 PRE-SWIZZLED in MFMA C-layout so the recurrence reads
// 8 B/lane fully coalesced:
//   P_sw elem index = ((((t*4 + bg)*16 + js)*4 + g)*64 + lane)*4 + r
// where value is for (b = bg*16 + (lane>>4)*4 + r, j = js*16 + (lane&15)).
// WG = 256 thr (4 waves). Tile: M = 16 batch x 4 t (wave w -> t0+w), N = 256
// (one gate). K = 256. MFMA fragment layouts (m89/m91/attention-verified):
//   A[m=lane&15][k=(lane>>4)*8 + j],  B[k=(lane>>4)*8+j][n=lane&15],
//   C col=lane&15, row=(lane>>4)*4+reg.
// ---------------------------------------------------------------------------
__global__ __launch_bounds__(256) void proj_kernel(
        const float* __restrict__ x,
        const unsigned short* __restrict__ WT,
        const float* __restrict__ biascat,
        unsigned short* __restrict__ Psw) {
    const int g  = blockIdx.x & 3;
    const int mt = blockIdx.x >> 2;       // 2048 M-tiles
    const int bg = mt & 3;
    const int t0 = (mt >> 2) << 2;        // 512 t-blocks * 4 t
    const int w  = threadIdx.x >> 6;      // wave -> tt
    const int L  = threadIdx.x & 63;
    const int t  = t0 + w;
    const int bb = bg * 16 + (L & 15);

    const float* xrow = x + ((size_t)bb * SEQ + t) * KDIM + ((L >> 4) * 8);

    f32x4 acc[16];
#pragma unroll
    for (int nn = 0; nn < 16; ++nn) acc[nn] = (f32x4){0.f, 0.f, 0.f, 0.f};

#pragma unroll
    for (int kt = 0; kt < 8; ++kt) {
        float4 xa = *(const float4*)(xrow + kt * 32);
        float4 xb = *(const float4*)(xrow + kt * 32 + 4);
        short8 af;
        af[0] = (short)f32_to_bf16_rne(xa.x);
        af[1] = (short)f32_to_bf16_rne(xa.y);
        af[2] = (short)f32_to_bf16_rne(xa.z);
        af[3] = (short)f32_to_bf16_rne(xa.w);
        af[4] = (short)f32_to_bf16_rne(xb.x);
        af[5] = (short)f32_to_bf16_rne(xb.y);
        af[6] = (short)f32_to_bf16_rne(xb.z);
        af[7] = (short)f32_to_bf16_rne(xb.w);
#pragma unroll
        for (int nn = 0; nn < 16; ++nn) {
            const short8 bf = *(const short8*)(WT +
                ((size_t)(g * 256 + nn * 16 + (L & 15))) * 256 + kt * 32 + ((L >> 4) * 8));
            acc[nn] = __builtin_amdgcn_mfma_f32_16x16x32_bf16(af, bf, acc[nn], 0, 0, 0);
        }
    }

#pragma unroll
    for (int nn = 0; nn < 16; ++nn) {
        float bv = biascat[g * 256 + nn * 16 + (L & 15)];
        unsigned short r0 = f32_to_bf16_rne(acc[nn][0] + bv);
        unsigned short r1 = f32_to_bf16_rne(acc[nn][1] + bv);
        unsigned short r2 = f32_to_bf16_rne(acc[nn][2] + bv);
        unsigned short r3 = f32_to_bf16_rne(acc[nn][3] + bv);
        uint2 pk;
        pk.x = (uint32_t)r0 | ((uint32_t)r1 << 16);
        pk.y = (uint32_t)r2 | ((uint32_t)r3 << 16);
        size_t off = (((((size_t)t * 4 + bg) * 16 + nn) * 4 + g) * 64 + L) * 4;
        *(uint2*)(Psw + off) = pk;
    }
}

// ---------------------------------------------------------------------------
// Recurrence: 64 WGs (bg = blockIdx>>4 in [0,4): batch group of 16;
// js = blockIdx&15: j-slice of 16 hidden cols). Wave w = gate. Per-wave
// weight slice K=256 x N=16 bf16 lives in 32 VGPRs for all 2048 steps.
// h double-buffered bf16 in ws. Per-WG publish flag; consumers poll the 16
// flags of their bg (one 64-B line, one coalesced load + ballot).
// ---------------------------------------------------------------------------
__global__ __launch_bounds__(256) void recur_kernel(
        const unsigned short* __restrict__ WhT,
        const unsigned short* __restrict__ Psw,
        unsigned short* __restrict__ hbuf,   // [2][64][256] bf16
        int* __restrict__ flags,             // [64] (bg*16 + js)
        float* __restrict__ out) {
    const int bg = blockIdx.x >> 4;
    const int js = blockIdx.x & 15;
    const int w  = threadIdx.x >> 6;   // gate
    const int L  = threadIdx.x & 63;

    __shared__ float plds[4 * 16 * 16];

    // Persistent weight fragments: B[k][n], n = w*256 + js*16 + (L&15)
    short8 wf[8];
    const size_t ncol = (size_t)(w * 256 + js * 16 + (L & 15));
#pragma unroll
    for (int kt = 0; kt < 8; ++kt)
        wf[kt] = *(const short8*)(WhT + ncol * 256 + kt * 32 + ((L >> 4) * 8));

    const int m_act = threadIdx.x >> 4;   // activation-phase (m, j) mapping
    const int j_act = threadIdx.x & 15;

    // h_0 = 0 into buffer 0 (flag-protected publish)
    hbuf[(size_t)(bg * 16 + m_act) * 256 + js * 16 + j_act] = 0;
    __syncthreads();
    if (threadIdx.x == 0)
        __hip_atomic_store(&flags[bg * 16 + js], 1, __ATOMIC_RELEASE, __HIP_MEMORY_SCOPE_AGENT);

    // P prefetch (P is independent of h -> loads hide under barrier wait)
    const size_t pstep = 65536;   // elems per t
    const size_t poff  = (((size_t)bg * 16 + js) * 4 + w) * 256 + (size_t)L * 4;
    uint2 pref = *(const uint2*)(Psw + poff);

    float c_st = 0.f, h_last = 0.f;
    bool timeout = false;

    for (int t = 0; t < SEQ; ++t) {
        // Wait until all 16 producers of this bg published h_t (flag >= t+1)
        const int need = t + 1;
        {
            int* fp = flags + bg * 16 + (L & 15);
            int spins = 0;
            for (;;) {
                int fl = (L < 16)
                    ? __hip_atomic_load(fp, __ATOMIC_RELAXED, __HIP_MEMORY_SCOPE_AGENT)
                    : need;
                if (__ballot(fl >= need) == ~0ull) break;
                if (++spins > 2000000) { timeout = true; break; }
            }
        }
        if (timeout) break;
        __builtin_amdgcn_fence(__ATOMIC_ACQUIRE, "agent");

        // A fragments: h_t rows of our batch group
        const unsigned short* hrow = hbuf + ((size_t)(t & 1)) * 16384 +
            (size_t)(bg * 16 + (L & 15)) * 256 + ((L >> 4) * 8);
        short8 af[8];
#pragma unroll
        for (int kt = 0; kt < 8; ++kt) af[kt] = *(const short8*)(hrow + kt * 32);

        f32x4 acc = (f32x4){0.f, 0.f, 0.f, 0.f};
#pragma unroll
        for (int kt = 0; kt < 8; ++kt)
            acc = __builtin_amdgcn_mfma_f32_16x16x32_bf16(af[kt], wf[kt], acc, 0, 0, 0);

        // Add precomputed projection (prefetched), prefetch next t
        uint2 pv = pref;
        if (t + 1 < SEQ) pref = *(const uint2*)(Psw + poff + (size_t)(t + 1) * pstep);
        acc[0] += bf16_to_f32((unsigned short)(pv.x & 0xFFFFu));
        acc[1] += bf16_to_f32((unsigned short)(pv.x >> 16));
        acc[2] += bf16_to_f32((unsigned short)(pv.y & 0xFFFFu));
        acc[3] += bf16_to_f32((unsigned short)(pv.y >> 16));

        // Cross-gate exchange via LDS (C-layout -> [gate][m][j])
#pragma unroll
        for (int r = 0; r < 4; ++r)
            plds[w * 256 + (((L >> 4) * 4 + r)) * 16 + (L & 15)] = acc[r];
        __syncthreads();

        float pi = plds[0 * 256 + m_act * 16 + j_act];
        float pf = plds[1 * 256 + m_act * 16 + j_act];
        float pg = plds[2 * 256 + m_act * 16 + j_act];
        float po = plds[3 * 256 + m_act * 16 + j_act];

        float ig = 1.f / (1.f + __expf(-pi));
        float fg = 1.f / (1.f + __expf(-pf));
        float pgc = fminf(fmaxf(pg, -30.f), 30.f);
        float eg  = __expf(2.f * pgc);
        float gg  = (eg - 1.f) / (eg + 1.f);
        float og = 1.f / (1.f + __expf(-po));

        c_st = fg * c_st + ig * gg;
        float ct = fminf(fmaxf(c_st, -30.f), 30.f);
        float e2 = __expf(2.f * ct);
        h_last = og * ((e2 - 1.f) / (e2 + 1.f));

        hbuf[((size_t)((t + 1) & 1)) * 16384 +
             (size_t)(bg * 16 + m_act) * 256 + js * 16 + j_act] = f32_to_bf16_rne(h_last);
        __syncthreads();   // waits vmcnt(0): all waves' h stores drained
        if (threadIdx.x == 0)
            __hip_atomic_store(&flags[bg * 16 + js], t + 2, __ATOMIC_RELEASE, __HIP_MEMORY_SCOPE_AGENT);
    }

    // Final outputs: h then c, fp32 [64][256] each
    size_t oidx = (size_t)(bg * 16 + m_act) * 256 + js * 16 + j_act;
    out[oidx]         = h_last;
    out[16384 + oidx] = c_st;
}

// ---------------------------------------------------------------------------
// Launch
// ---------------------------------------------------------------------------
extern "C" void kernel_launch(void* const* d_in, const int* in_sizes, int n_in,
                              void* d_out, int out_size, void* d_ws, size_t ws_size,
                              hipStream_t stream) {
    (void)in_sizes; (void)n_in; (void)out_size; (void)ws_size;
    const float* x = (const float*)d_in[0];

    // Workspace carve (total ~269.5 MB)
    char* ws = (char*)d_ws;
    const size_t PSW_BYTES = (size_t)SEQ * 65536 * 2;       // 268,435,456
    unsigned short* Psw     = (unsigned short*)ws;
    unsigned short* WT      = (unsigned short*)(ws + PSW_BYTES);
    unsigned short* WhT     = (unsigned short*)(ws + PSW_BYTES + 524288);
    float*          biascat = (float*)(ws + PSW_BYTES + 1048576);
    unsigned short* hbuf    = (unsigned short*)(ws + PSW_BYTES + 1048576 + 4096);
    int*            flags   = (int*)(ws + PSW_BYTES + 1048576 + 4096 + 65536);

    hipMemsetAsync(flags, 0, 256, stream);

    PrepArgs pa;
    pa.Wi[0] = (const float*)d_in[1];  pa.Wh[0] = (const float*)d_in[2];
    pa.bi[0] = (const float*)d_in[3];  pa.bh[0] = (const float*)d_in[4];
    pa.Wi[1] = (const float*)d_in[5];  pa.Wh[1] = (const float*)d_in[6];
    pa.bi[1] = (const float*)d_in[7];  pa.bh[1] = (const float*)d_in[8];
    pa.Wi[2] = (const float*)d_in[9];  pa.Wh[2] = (const float*)d_in[10];
    pa.bi[2] = (const float*)d_in[11]; pa.bh[2] = (const float*)d_in[12];
    pa.Wi[3] = (const float*)d_in[13]; pa.Wh[3] = (const float*)d_in[14];
    pa.bi[3] = (const float*)d_in[15]; pa.bh[3] = (const float*)d_in[16];
    pa.WT = WT; pa.WhT = WhT; pa.biascat = biascat;
    prep_kernel<<<2052, 256, 0, stream>>>(pa);

    proj_kernel<<<8192, 256, 0, stream>>>(x, WT, biascat, Psw);

    const unsigned short* WhT_c = WhT;
    const unsigned short* Psw_c = Psw;
    unsigned short* hbuf_c = hbuf;
    int* flags_c = flags;
    float* out_c = (float*)d_out;
    void* kargs[] = { &WhT_c, &Psw_c, &hbuf_c, &flags_c, &out_c };
    hipLaunchCooperativeKernel((void*)recur_kernel, dim3(64), dim3(256),
                               kargs, 0, stream);
}

// Round 3
// 7338.869 us; speedup vs baseline: 1.6856x; 1.6856x over previous
//
#include <hip/hip_runtime.h>
#include <hip/hip_bf16.h>
#include <stdint.h>

// Problem constants
#define BATCH 64
#define SEQ   2048
#define KDIM  256
#define HIDD  256

typedef __attribute__((ext_vector_type(8))) short short8;
typedef __attribute__((ext_vector_type(4))) float f32x4;
typedef __attribute__((ext_vector_type(2))) unsigned int uint2v;   // clang-native, ok for nontemporal builtins
typedef __attribute__((ext_vector_type(4))) float f32x4v;          // clang-native

__device__ __forceinline__ unsigned short f32_to_bf16_rne(float f) {
    union { float f; uint32_t u; } v; v.f = f;
    uint32_t u = v.u;
    uint32_t r = (u + 0x7FFFu + ((u >> 16) & 1u)) >> 16;
    return (unsigned short)r;
}
__device__ __forceinline__ float bf16_to_f32(unsigned short h) {
    union { float f; uint32_t u; } v; v.u = ((uint32_t)h) << 16;
    return v.f;
}

// ---------------------------------------------------------------------------
// Prep: transpose+cast weights to bf16 [n][k] layout (n = gate*256 + j), and
// fold biases (b_i + b_h) into a single [1024] fp32 vector.
// ---------------------------------------------------------------------------
struct PrepArgs {
    const float* Wi[4];
    const float* Wh[4];
    const float* bi[4];
    const float* bh[4];
    unsigned short* WT;    // [1024][256] bf16, from W_i*
    unsigned short* WhT;   // [1024][256] bf16, from W_h*
    float* biascat;        // [1024] fp32
};

__global__ __launch_bounds__(256) void prep_kernel(PrepArgs a) {
    int blk = blockIdx.x, tid = threadIdx.x;
    if (blk < 1024) {
        int n = blk, g = n >> 8, j = n & 255, k = tid;
        a.WT[(size_t)n * 256 + k] = f32_to_bf16_rne(a.Wi[g][(size_t)k * 256 + j]);
    } else if (blk < 2048) {
        int n = blk - 1024, g = n >> 8, j = n & 255, k = tid;
        a.WhT[(size_t)n * 256 + k] = f32_to_bf16_rne(a.Wh[g][(size_t)k * 256 + j]);
    } else if (blk < 2052) {
        int n = (blk - 2048) * 256 + tid;
        int g = n >> 8, j = n & 255;
        a.biascat[n] = a.bi[g][j] + a.bh[g][j];
    }
}

// ---------------------------------------------------------------------------
// Projection GEMM v2: one WG per (t, half) covering 32 batches x all 4 gates.
// x staged once in LDS (coalesced, read exactly once globally -> nontemporal);
// wave w = gate w; B-fragment reused across 2 M-tiles. Psw layout:
//   P_sw elem index = ((((t*4 + bg)*16 + js)*4 + g)*64 + lane)*4 + r
//   value for (b = bg*16 + (lane>>4)*4 + r, j = js*16 + (lane&15)).
// MFMA layouts (verified round 1): A[m=lane&15][k=(lane>>4)*8+i],
// B[k=(lane>>4)*8+i][n=lane&15], C col=lane&15, row=(lane>>4)*4+reg.
// ---------------------------------------------------------------------------
__global__ __launch_bounds__(256, 2) void proj_kernel(
        const float* __restrict__ x,
        const unsigned short* __restrict__ WT,
        const float* __restrict__ biascat,
        unsigned short* __restrict__ Psw) {
    const int t    = blockIdx.x >> 1;
    const int half = blockIdx.x & 1;      // batches half*32 .. half*32+31
    const int w    = threadIdx.x >> 6;    // gate
    const int L    = threadIdx.x & 63;

    __shared__ unsigned short xt[32][272]; // +16 pad: 16B-aligned rows, 0-conflict

    // Stage x tile: 32 rows x 256 k, fp32 -> bf16, coalesced, nontemporal.
    {
        const int r = threadIdx.x >> 3;   // 0..31
        const int q = threadIdx.x & 7;    // float4 chunk
        const float* xr = x + ((size_t)(half * 32 + r) * SEQ + t) * KDIM;
#pragma unroll
        for (int it = 0; it < 8; ++it) {
            int c = q * 4 + it * 32;
            f32x4v v = __builtin_nontemporal_load((const f32x4v*)(xr + c));
            xt[r][c + 0] = f32_to_bf16_rne(v.x);
            xt[r][c + 1] = f32_to_bf16_rne(v.y);
            xt[r][c + 2] = f32_to_bf16_rne(v.z);
            xt[r][c + 3] = f32_to_bf16_rne(v.w);
        }
    }
    __syncthreads();

    f32x4 acc[2][16];
#pragma unroll
    for (int m = 0; m < 2; ++m)
#pragma unroll
        for (int nn = 0; nn < 16; ++nn) acc[m][nn] = (f32x4){0.f, 0.f, 0.f, 0.f};

#pragma unroll
    for (int kt = 0; kt < 8; ++kt) {
        const int kc = kt * 32 + ((L >> 4) * 8);
        short8 a0 = *(const short8*)&xt[(L & 15)][kc];
        short8 a1 = *(const short8*)&xt[16 + (L & 15)][kc];
#pragma unroll
        for (int nn = 0; nn < 16; ++nn) {
            const short8 bf = *(const short8*)(WT +
                ((size_t)(w * 256 + nn * 16 + (L & 15))) * 256 + kc);
            acc[0][nn] = __builtin_amdgcn_mfma_f32_16x16x32_bf16(a0, bf, acc[0][nn], 0, 0, 0);
            acc[1][nn] = __builtin_amdgcn_mfma_f32_16x16x32_bf16(a1, bf, acc[1][nn], 0, 0, 0);
        }
    }

#pragma unroll
    for (int mt2 = 0; mt2 < 2; ++mt2) {
        const int bg = half * 2 + mt2;
#pragma unroll
        for (int nn = 0; nn < 16; ++nn) {
            float bv = biascat[w * 256 + nn * 16 + (L & 15)];
            unsigned short r0 = f32_to_bf16_rne(acc[mt2][nn][0] + bv);
            unsigned short r1 = f32_to_bf16_rne(acc[mt2][nn][1] + bv);
            unsigned short r2 = f32_to_bf16_rne(acc[mt2][nn][2] + bv);
            unsigned short r3 = f32_to_bf16_rne(acc[mt2][nn][3] + bv);
            uint2v pk;
            pk.x = (uint32_t)r0 | ((uint32_t)r1 << 16);
            pk.y = (uint32_t)r2 | ((uint32_t)r3 << 16);
            size_t off = (((((size_t)t * 4 + bg) * 16 + nn) * 4 + w) * 64 + L) * 4;
            __builtin_nontemporal_store(pk, (uint2v*)(Psw + off));
        }
    }
}

// ---------------------------------------------------------------------------
// Recurrence v2: same topology (64 WGs: bg = blk>>4, js = blk&15, wave=gate),
// but ALL cross-WG traffic uses relaxed AGENT-scope atomics (sc0/sc1
// write-through/bypass) -- NO buffer_wbl2 / buffer_inv cache walks.
// Ordering: each wave's sc1 stores are drained (vmcnt 0) by the compiler
// before s_barrier; flag store issues after -> release semantics for free.
// Consumer h-loads are program-ordered after the poll branch and bypass
// L1/L2, so they observe IC contents newer than the flag -> acquire for free.
// ---------------------------------------------------------------------------
__global__ __launch_bounds__(256) void recur_kernel(
        const unsigned short* __restrict__ WhT,
        const unsigned short* __restrict__ Psw,
        unsigned short* __restrict__ hbuf,   // [2][64][256] bf16
        int* __restrict__ flags,             // [64] (bg*16 + js)
        float* __restrict__ out) {
    const int bg = blockIdx.x >> 4;
    const int js = blockIdx.x & 15;
    const int w  = threadIdx.x >> 6;   // gate
    const int L  = threadIdx.x & 63;

    __shared__ float plds[4 * 16 * 16];

    // Persistent weight fragments: B[k][n], n = w*256 + js*16 + (L&15)
    short8 wf[8];
    const size_t ncol = (size_t)(w * 256 + js * 16 + (L & 15));
#pragma unroll
    for (int kt = 0; kt < 8; ++kt)
        wf[kt] = *(const short8*)(WhT + ncol * 256 + kt * 32 + ((L >> 4) * 8));

    const int m_act = threadIdx.x >> 4;   // activation-phase (m, j) mapping
    const int j_act = threadIdx.x & 15;

    uint32_t* hb32 = (uint32_t*)hbuf;

    // h_0 = 0 into buffer 0 (agent-scope write-through stores, packed pairs)
    if ((j_act & 1) == 0) {
        size_t eidx = ((size_t)(bg * 16 + m_act) * 256 + js * 16 + j_act) >> 1;
        __hip_atomic_store(&hb32[eidx], 0u, __ATOMIC_RELAXED, __HIP_MEMORY_SCOPE_AGENT);
    }
    __syncthreads();   // drains vmcnt(0) per wave -> h0 at IC before flag
    if (threadIdx.x == 0)
        __hip_atomic_store(&flags[bg * 16 + js], 1, __ATOMIC_RELAXED, __HIP_MEMORY_SCOPE_AGENT);

    // P prefetch (independent of h -> hides under barrier/poll wait).
    // Nontemporal: P is read exactly once; keep it out of IC's hot set.
    const size_t pstep = 65536;   // elems per t
    const size_t poff  = (((size_t)bg * 16 + js) * 4 + w) * 256 + (size_t)L * 4;
    uint2v pref = __builtin_nontemporal_load((const uint2v*)(Psw + poff));

    float c_st = 0.f, h_last = 0.f;
    bool timeout = false;

    for (int t = 0; t < SEQ; ++t) {
        // Wait until all 16 producers of this bg published h_t (flag >= t+1)
        const int need = t + 1;
        {
            int* fp = flags + bg * 16 + (L & 15);
            int spins = 0;
            for (;;) {
                int fl = (L < 16)
                    ? __hip_atomic_load(fp, __ATOMIC_RELAXED, __HIP_MEMORY_SCOPE_AGENT)
                    : need;
                if (__ballot(fl >= need) == ~0ull) break;
                if (++spins > 2000000) { timeout = true; break; }
            }
        }
        if (timeout) break;
        asm volatile("" ::: "memory");   // compiler-only ordering barrier

        // A fragments: h_t rows of our batch group (agent-scope bypass loads)
        const size_t hbase = ((size_t)(t & 1)) * 16384 +
            (size_t)(bg * 16 + (L & 15)) * 256 + ((L >> 4) * 8);
        short8 af[8];
#pragma unroll
        for (int kt = 0; kt < 8; ++kt) {
            const unsigned long long* hp =
                (const unsigned long long*)(hbuf + hbase + kt * 32);
            union { unsigned long long q[2]; short8 s; } cv;
            cv.q[0] = __hip_atomic_load(hp,     __ATOMIC_RELAXED, __HIP_MEMORY_SCOPE_AGENT);
            cv.q[1] = __hip_atomic_load(hp + 1, __ATOMIC_RELAXED, __HIP_MEMORY_SCOPE_AGENT);
            af[kt] = cv.s;
        }

        f32x4 acc = (f32x4){0.f, 0.f, 0.f, 0.f};
#pragma unroll
        for (int kt = 0; kt < 8; ++kt)
            acc = __builtin_amdgcn_mfma_f32_16x16x32_bf16(af[kt], wf[kt], acc, 0, 0, 0);

        // Add precomputed projection (prefetched), prefetch next t
        uint2v pv = pref;
        if (t + 1 < SEQ)
            pref = __builtin_nontemporal_load(
                (const uint2v*)(Psw + poff + (size_t)(t + 1) * pstep));
        acc[0] += bf16_to_f32((unsigned short)(pv.x & 0xFFFFu));
        acc[1] += bf16_to_f32((unsigned short)(pv.x >> 16));
        acc[2] += bf16_to_f32((unsigned short)(pv.y & 0xFFFFu));
        acc[3] += bf16_to_f32((unsigned short)(pv.y >> 16));

        // Cross-gate exchange via LDS (C-layout -> [gate][m][j])
#pragma unroll
        for (int r = 0; r < 4; ++r)
            plds[w * 256 + (((L >> 4) * 4 + r)) * 16 + (L & 15)] = acc[r];
        __syncthreads();

        float pi = plds[0 * 256 + m_act * 16 + j_act];
        float pf = plds[1 * 256 + m_act * 16 + j_act];
        float pg = plds[2 * 256 + m_act * 16 + j_act];
        float po = plds[3 * 256 + m_act * 16 + j_act];

        float ig = 1.f / (1.f + __expf(-pi));
        float fg = 1.f / (1.f + __expf(-pf));
        float pgc = fminf(fmaxf(pg, -30.f), 30.f);
        float eg  = __expf(2.f * pgc);
        float gg  = (eg - 1.f) / (eg + 1.f);
        float og = 1.f / (1.f + __expf(-po));

        c_st = fg * c_st + ig * gg;
        float ct = fminf(fmaxf(c_st, -30.f), 30.f);
        float e2 = __expf(2.f * ct);
        h_last = og * ((e2 - 1.f) / (e2 + 1.f));

        // Publish h_{t+1}: pack bf16 pair with lane^1 partner, even lanes
        // store 4B agent-scope (write-through to IC).
        {
            uint32_t hb = (uint32_t)f32_to_bf16_rne(h_last);
            uint32_t pt = (uint32_t)__shfl_xor((int)hb, 1, 64);
            if ((j_act & 1) == 0) {
                uint32_t val = hb | (pt << 16);
                size_t eidx = (((size_t)((t + 1) & 1)) * 16384 +
                               (size_t)(bg * 16 + m_act) * 256 + js * 16 + j_act) >> 1;
                __hip_atomic_store(&hb32[eidx], val,
                                   __ATOMIC_RELAXED, __HIP_MEMORY_SCOPE_AGENT);
            }
        }
        __syncthreads();   // vmcnt(0): all waves' sc1 h stores at IC
        if (threadIdx.x == 0)
            __hip_atomic_store(&flags[bg * 16 + js], t + 2,
                               __ATOMIC_RELAXED, __HIP_MEMORY_SCOPE_AGENT);
    }

    // Final outputs: h then c, fp32 [64][256] each
    size_t oidx = (size_t)(bg * 16 + m_act) * 256 + js * 16 + j_act;
    out[oidx]         = h_last;
    out[16384 + oidx] = c_st;
}

// ---------------------------------------------------------------------------
// Launch
// ---------------------------------------------------------------------------
extern "C" void kernel_launch(void* const* d_in, const int* in_sizes, int n_in,
                              void* d_out, int out_size, void* d_ws, size_t ws_size,
                              hipStream_t stream) {
    (void)in_sizes; (void)n_in; (void)out_size; (void)ws_size;
    const float* x = (const float*)d_in[0];

    // Workspace carve (total ~269.5 MB)
    char* ws = (char*)d_ws;
    const size_t PSW_BYTES = (size_t)SEQ * 65536 * 2;       // 268,435,456
    unsigned short* Psw     = (unsigned short*)ws;
    unsigned short* WT      = (unsigned short*)(ws + PSW_BYTES);
    unsigned short* WhT     = (unsigned short*)(ws + PSW_BYTES + 524288);
    float*          biascat = (float*)(ws + PSW_BYTES + 1048576);
    unsigned short* hbuf    = (unsigned short*)(ws + PSW_BYTES + 1048576 + 4096);
    int*            flags   = (int*)(ws + PSW_BYTES + 1048576 + 4096 + 65536);

    (void)hipMemsetAsync(flags, 0, 256, stream);

    PrepArgs pa;
    pa.Wi[0] = (const float*)d_in[1];  pa.Wh[0] = (const float*)d_in[2];
    pa.bi[0] = (const float*)d_in[3];  pa.bh[0] = (const float*)d_in[4];
    pa.Wi[1] = (const float*)d_in[5];  pa.Wh[1] = (const float*)d_in[6];
    pa.bi[1] = (const float*)d_in[7];  pa.bh[1] = (const float*)d_in[8];
    pa.Wi[2] = (const float*)d_in[9];  pa.Wh[2] = (const float*)d_in[10];
    pa.bi[2] = (const float*)d_in[11]; pa.bh[2] = (const float*)d_in[12];
    pa.Wi[3] = (const float*)d_in[13]; pa.Wh[3] = (const float*)d_in[14];
    pa.bi[3] = (const float*)d_in[15]; pa.bh[3] = (const float*)d_in[16];
    pa.WT = WT; pa.WhT = WhT; pa.biascat = biascat;
    prep_kernel<<<2052, 256, 0, stream>>>(pa);

    proj_kernel<<<4096, 256, 0, stream>>>(x, WT, biascat, Psw);

    const unsigned short* WhT_c = WhT;
    const unsigned short* Psw_c = Psw;
    unsigned short* hbuf_c = hbuf;
    int* flags_c = flags;
    float* out_c = (float*)d_out;
    void* kargs[] = { &WhT_c, &Psw_c, &hbuf_c, &flags_c, &out_c };
    (void)hipLaunchCooperativeKernel((void*)recur_kernel, dim3(64), dim3(256),
                                     kargs, 0, stream);
}